// Round 12
// baseline (78.417 us; speedup 1.0000x reference)
//
#include <hip/hip_runtime.h>
#include <math.h>

// ---------------------------------------------------------------------------
// MultiRoundDistribution MCMC — bit-exact JAX PRNG (partitionable threefry).
// Round 12: 2-STEP SPECULATION. r2-r11 scaling law: wall ~ (# serial
// dependency segments) x ~1.2us, nearly invariant to per-segment work. So cut
// segments 48 -> 24: per group evaluate chain S (step s), chain R (step s+1 |
// reject), chain A (step s+1 | accept, reusing fS=e*feS so decisions stay
// bit-exact), resolve with selects, update state via factor selection
// (exact in 3/4 cases; 1-ulp reassociation in {acc,acc} — 1e-16/group drift,
// 9 orders below the decision-robustness band).
// draw/table kernels unchanged from r9 (proven bit-exact).
// ---------------------------------------------------------------------------

constexpr int kN = 16384;
constexpr int kL = 48;
constexpr int kM = 4;
constexpr int kR = 7;
constexpr int kSteps = 48;  // n_sweeps(=1) * L

// ---- d_ws layout (same as rounds 7-9) ----
constexpr int ROWS_OFF = 0;                       // 768 rows x 80B (site*1280 + nc*320 + oldc*80)
constexpr int SING_OFF = 61440;                   // 48*4 x 64B (exp singles)
constexpr int META_OFF = 73728;                   // 50 x {u32 rowbase, u32 site}
constexpr int BB_OFF   = 74128;                   // 21 doubles (b1,b2,b3 per round)
constexpr int TAB_BYTES = 74752;
constexpr int DRAWS_OFF = 74752;                  // 48*16384 u32

// ---------------- Threefry-2x32 (JAX rotation schedule) ----------------
#define TF_ROUND(rot) do { x0 += x1; x1 = (x1 << (rot)) | (x1 >> (32 - (rot))); x1 ^= x0; } while (0)

__device__ __forceinline__ void tf2(unsigned ka, unsigned kb,
                                    unsigned x0, unsigned x1,
                                    unsigned& o0, unsigned& o1) {
  const unsigned ks2 = ka ^ kb ^ 0x1BD11BDAu;
  x0 += ka; x1 += kb;
  TF_ROUND(13); TF_ROUND(15); TF_ROUND(26); TF_ROUND(6);
  x0 += kb; x1 += ks2 + 1u;
  TF_ROUND(17); TF_ROUND(29); TF_ROUND(16); TF_ROUND(24);
  x0 += ks2; x1 += ka + 2u;
  TF_ROUND(13); TF_ROUND(15); TF_ROUND(26); TF_ROUND(6);
  x0 += ka; x1 += kb + 3u;
  TF_ROUND(17); TF_ROUND(29); TF_ROUND(16); TF_ROUND(24);
  x0 += kb; x1 += ks2 + 4u;
  TF_ROUND(13); TF_ROUND(15); TF_ROUND(26); TF_ROUND(6);
  x0 += ks2; x1 += ka + 5u;
  o0 = x0; o1 = x1;
}

__device__ __forceinline__ unsigned rb32(unsigned ka, unsigned kb, unsigned i) {
  unsigned o0, o1; tf2(ka, kb, 0u, i, o0, o1); return o0 ^ o1;
}

__device__ __forceinline__ double pow7(double x) {
  const double x2 = x * x, x4 = x2 * x2;
  return x4 * x2 * x;
}

__device__ __forceinline__ unsigned catAt(unsigned w0, unsigned w1, unsigned w2,
                                          unsigned site) {
  const unsigned ww = (site < 16u) ? w0 : ((site < 32u) ? w1 : w2);
  return (ww >> (2u * (site & 15u))) & 3u;
}

__device__ __forceinline__ unsigned site_from_key(unsigned s) {
  unsigned ka, kb;  tf2(0u, 42u, 0u, s, ka, kb);
  unsigned i0, i1, h1a, h1b, l1a, l1b;
  tf2(ka, kb, 0u, 0u, i0, i1);
  tf2(i0, i1, 0u, 0u, h1a, h1b);
  tf2(i0, i1, 0u, 1u, l1a, l1b);
  const unsigned hb = rb32(h1a, h1b, 0u);
  const unsigned lb = rb32(l1a, l1b, 0u);
  return ((hb % 48u) * 16u + (lb % 48u)) % 48u;
}

// ---------------- phase 1: draws + tables (verbatim r9) ----------------
__global__ __launch_bounds__(256)
void draw_kernel(const float* __restrict__ h0, const float* __restrict__ modes_h,
                 const void* __restrict__ selp, unsigned char* __restrict__ ws) {
  const unsigned by = blockIdx.y;
  const unsigned t = threadIdx.x;
  if (by < (unsigned)kSteps) {
    __shared__ unsigned k4[4];
    if (t == 0u) {
      unsigned ka, kb, r0, r1, a0, a1, c0, c1;
      tf2(0u, 42u, 0u, by, ka, kb);                         // split(key(42),48)[s]
      tf2(ka, kb, 0u, 1u, r0, r1);                          // k_res
      tf2(ka, kb, 0u, 2u, a0, a1);                          // k_acc
      tf2(r0, r1, 0u, 1u, c0, c1);                          // k2 of split(k_res,2)
      k4[0] = c0; k4[1] = c1; k4[2] = a0; k4[3] = a1;
    }
    __syncthreads();
    const unsigned n = blockIdx.x * 256u + t;
    const unsigned nc = rb32(k4[0], k4[1], n) & 3u;
    const unsigned ub = rb32(k4[2], k4[3], n);
    ((unsigned*)(ws + DRAWS_OFF))[by * (unsigned)kN + n] = (ub & 0xFFFFFE00u) | nc;
    return;
  }
  if (blockIdx.x != 0) return;

  __shared__ unsigned ss[kSteps];
  __shared__ double exl[kL][5][4][2];   // [l][field: h,m0..3][cat][{+,-}]

  if (t < (unsigned)kSteps) ss[t] = site_from_key(t);
  if (t < 240u) {
    const int l = t / 5, k = t % 5;
#pragma unroll
    for (int c = 0; c < 4; ++c) {
      const double v = (k == 0) ? (double)h0[l * 4 + c]
                                : (double)modes_h[((k - 1) * kL + l) * 4 + c];
      exl[l][k][c][0] = exp(v);
      exl[l][k][c][1] = exp(-v);
    }
  }
  if (t == 255u) {
    const unsigned* wp = (const unsigned*)selp;
    int mode;
    if (wp[0] == 0x3F800000u) mode = 0;
    else {
      mode = 1;
      for (int i = 0; i < kR * kM; ++i) if (wp[i] > 1u) { mode = 2; break; }
    }
    double* bbw = (double*)(ws + BB_OFF);
    for (int r = 0; r < kR; ++r)
      for (int m = 1; m < kM; ++m) {
        const int i = r * 4 + m;
        unsigned b;
        if (mode == 0)      b = (wp[i] == 0x3F800000u) ? 1u : 0u;
        else if (mode == 1) b = wp[i] ? 1u : 0u;
        else                b = ((const unsigned char*)selp)[i] ? 1u : 0u;
        bbw[r * 3 + (m - 1)] = b ? 1.0 : 0.0;
      }
  }
  __syncthreads();

  if (t < (unsigned)kSteps) {
    unsigned* meta = (unsigned*)(ws + META_OFF);
    meta[2 * t]     = ss[t] * 1280u;
    meta[2 * t + 1] = ss[t];
    if (t == 0u) {
      meta[2 * 48] = ss[47] * 1280u;  meta[2 * 48 + 1] = ss[47];
      meta[2 * 49] = ss[47] * 1280u;  meta[2 * 49 + 1] = ss[47];
    }
  }
  for (int R = t; R < kL * 16; R += 256) {
    const int l = R >> 4, idx = R & 15, nw = idx >> 2, od = idx & 3;
    double* row = (double*)(ws + ROWS_OFF + (size_t)R * 80);
#pragma unroll
    for (int m = 0; m < 4; ++m) {
      row[m]     = exl[l][1 + m][nw][0] * exl[l][1 + m][od][1];  // fe_m
      row[4 + m] = exl[l][1 + m][nw][1] * exl[l][1 + m][od][0];  // fd_m
    }
    row[8] = exl[l][0][nw][0] * exl[l][0][od][1];                // fh
    row[9] = 0.0;
  }
  if (t < 192u) {
    const int l = t >> 2, c = t & 3;
    double* sg = (double*)(ws + SING_OFF + (size_t)(l * 4 + c) * 64);
#pragma unroll
    for (int m = 0; m < 4; ++m) {
      sg[2 * m]     = exl[l][1 + m][c][0];
      sg[2 * m + 1] = exl[l][1 + m][c][1];
    }
  }
}

// ---------------- row load helper ----------------
struct Row { double2 e01, e23, d01, d23; double h; };
__device__ __forceinline__ Row ldrow(const char* p) {
  Row r;
  r.e01 = *(const double2*)(p);
  r.e23 = *(const double2*)(p + 16);
  r.d01 = *(const double2*)(p + 32);
  r.d23 = *(const double2*)(p + 48);
  r.h   = *(const double*)(p + 64);
  return r;
}

// PQ from f/g values (bit-identical ordering to r10/r11)
__device__ __forceinline__ double chainPQ(double f0, double f1, double f2, double f3,
                                          double g0, double g1, double g2, double g3,
                                          const bool* m1, const bool* m2,
                                          const bool* m3) {
  double se[kR];
#pragma unroll
  for (int r = 0; r < kR; ++r) {
    const double s1 = m1[r] ? f1 : 0.0;
    const double s2 = m2[r] ? f2 : 0.0;
    const double s3 = m3[r] ? f3 : 0.0;
    se[r] = (f0 + s1) + (s2 + s3);
  }
  return (pow7((g0 + g1) + (g2 + g3)) *
          ((se[0] * se[1]) * (se[2] * se[3]))) *
         ((se[4] * se[5]) * se[6]);
}

// ---------------- phase 2: MCMC with 2-step speculation ----------------
__global__ __launch_bounds__(64)
void mcmc_spec(const float* __restrict__ chains, const unsigned char* __restrict__ ws,
               float* __restrict__ out) {
  __shared__ __align__(16) char sTab[TAB_BYTES];
  __shared__ unsigned sDraws[kSteps * 64];

  const int tid = threadIdx.x;
  const int n = blockIdx.x * 64 + tid;

  // ---- stage tables + draws into LDS ----
  {
    const float4* gt = (const float4*)(ws + ROWS_OFF);
    float4* lt = (float4*)sTab;
    for (int i = tid; i < TAB_BYTES / 16; i += 64) lt[i] = gt[i];
    const unsigned* gd = (const unsigned*)(ws + DRAWS_OFF);
    for (int s = 0; s < kSteps; ++s)
      sDraws[s * 64 + tid] = gd[(size_t)s * kN + n];
  }

  // ---- decode chain state (overlaps staging latency) ----
  unsigned w0 = 0, w1 = 0, w2 = 0;
  {
    const float4* ch = (const float4*)(chains + (size_t)n * (kL * 4));
#pragma unroll
    for (int l = 0; l < kL; ++l) {
      const float4 v = ch[l];
      const unsigned c = (v.y > 0.5f) ? 1u : ((v.z > 0.5f) ? 2u : ((v.w > 0.5f) ? 3u : 0u));
      const unsigned sh = 2u * (unsigned)(l & 15);
      if (l < 16) w0 |= c << sh; else if (l < 32) w1 |= c << sh; else w2 |= c << sh;
    }
  }
  __syncthreads();

  // ---- selection masks as wave-uniform bools (b0 == 1 by construction) ----
  bool m1[kR], m2[kR], m3[kR];
  {
    const double* bbw = (const double*)(sTab + BB_OFF);
#pragma unroll
    for (int r = 0; r < kR; ++r) {
      m1[r] = bbw[r * 3 + 0] != 0.0;
      m2[r] = bbw[r * 3 + 1] != 0.0;
      m3[r] = bbw[r * 3 + 2] != 0.0;
    }
  }

  // ---- initial multiplicative state from singles ----
  double e0 = 1.0, e1 = 1.0, e2 = 1.0, e3 = 1.0;
  double d0 = 1.0, d1 = 1.0, d2 = 1.0, d3 = 1.0;
#pragma unroll 4
  for (int l = 0; l < kL; ++l) {
    const unsigned c = catAt(w0, w1, w2, (unsigned)l);
    const double* sg = (const double*)(sTab + SING_OFF + (size_t)(l * 4 + c) * 64);
    e0 *= sg[0]; d0 *= sg[1];  e1 *= sg[2]; d1 *= sg[3];
    e2 *= sg[4]; d2 *= sg[5];  e3 *= sg[6]; d3 *= sg[7];
  }
  double Dd = pow7((d0 + d1) + (d2 + d3));
#pragma unroll
  for (int r = 0; r < kR; ++r) {
    const double s1 = m1[r] ? e1 : 0.0;
    const double s2 = m2[r] ? e2 : 0.0;
    const double s3 = m3[r] ? e3 : 0.0;
    Dd *= ((e0 + s1) + (s2 + s3));
  }

  const unsigned* meta = (const unsigned*)(sTab + META_OFF);

  // ---- 24 groups of 2 speculated steps ----
  for (int g = 0; g < kSteps / 2; ++g) {
    const int s0 = 2 * g, s1 = 2 * g + 1;
    const unsigned base0 = meta[2 * s0], site0 = meta[2 * s0 + 1];
    const unsigned base1 = meta[2 * s1], site1 = meta[2 * s1 + 1];
    const unsigned dw0 = sDraws[s0 * 64 + tid];
    const unsigned dw1 = sDraws[s1 * 64 + tid];
    const unsigned nc0 = dw0 & 3u, nc1 = dw1 & 3u;

    // addresses for all three chains (independent of f64 state)
    const unsigned oldc0 = catAt(w0, w1, w2, site0);
    const unsigned sh0 = 2u * (site0 & 15u);
    const unsigned mb0 = 3u << sh0, nv0 = nc0 << sh0;
    const unsigned wp0 = (site0 < 16u) ? ((w0 & ~mb0) | nv0) : w0;
    const unsigned wp1 = (site0 >= 16u && site0 < 32u) ? ((w1 & ~mb0) | nv0) : w1;
    const unsigned wp2 = (site0 >= 32u) ? ((w2 & ~mb0) | nv0) : w2;
    const unsigned oldcR = catAt(w0, w1, w2, site1);
    const unsigned oldcA = catAt(wp0, wp1, wp2, site1);

    const Row S = ldrow(sTab + base0 + nc0 * 320u + oldc0 * 80u);
    const Row R = ldrow(sTab + base1 + nc1 * 320u + oldcR * 80u);
    const Row A = ldrow(sTab + base1 + nc1 * 320u + oldcA * 80u);

    const float r0f = __uint_as_float((dw0 >> 9) | 0x3F800000u) - 1.0f;
    const float r1f = __uint_as_float((dw1 >> 9) | 0x3F800000u) - 1.0f;

    // chain S (step s0) — shared fS/gS
    const double fS0 = e0 * S.e01.x, fS1 = e1 * S.e01.y;
    const double fS2 = e2 * S.e23.x, fS3 = e3 * S.e23.y;
    const double gS0 = d0 * S.d01.x, gS1 = d1 * S.d01.y;
    const double gS2 = d2 * S.d23.x, gS3 = d3 * S.d23.y;
    const double PQ0 = chainPQ(fS0, fS1, fS2, fS3, gS0, gS1, gS2, gS3, m1, m2, m3);
    const bool acc0 = (S.h * PQ0) > (double)r0f * Dd;

    // chain R (step s1 | s0 rejected)
    const double fR0 = e0 * R.e01.x, fR1 = e1 * R.e01.y;
    const double fR2 = e2 * R.e23.x, fR3 = e3 * R.e23.y;
    const double gR0 = d0 * R.d01.x, gR1 = d1 * R.d01.y;
    const double gR2 = d2 * R.d23.x, gR3 = d3 * R.d23.y;
    const double PQR = chainPQ(fR0, fR1, fR2, fR3, gR0, gR1, gR2, gR3, m1, m2, m3);
    const bool bR = (R.h * PQR) > (double)r1f * Dd;

    // chain A (step s1 | s0 accepted) — bit-exact sequential values via fS
    const double fA0 = fS0 * A.e01.x, fA1 = fS1 * A.e01.y;
    const double fA2 = fS2 * A.e23.x, fA3 = fS3 * A.e23.y;
    const double gA0 = gS0 * A.d01.x, gA1 = gS1 * A.d01.y;
    const double gA2 = gS2 * A.d23.x, gA3 = gS3 * A.d23.y;
    const double PQA = chainPQ(fA0, fA1, fA2, fA3, gA0, gA1, gA2, gA3, m1, m2, m3);
    const bool bA = (A.h * PQA) > (double)r1f * PQ0;

    const bool acc1 = acc0 ? bA : bR;

    // state update via factor selection
    // {acc0,bA}: feS*feA (1-ulp reassoc vs sequential; decisions unaffected)
    // {acc0,!bA}: feS   {!acc0,bR}: feR   {!acc0,!bR}: 1.0   — all exact
    const double fe0c = acc0 ? (bA ? S.e01.x * A.e01.x : S.e01.x)
                             : (bR ? R.e01.x : 1.0);
    const double fe1c = acc0 ? (bA ? S.e01.y * A.e01.y : S.e01.y)
                             : (bR ? R.e01.y : 1.0);
    const double fe2c = acc0 ? (bA ? S.e23.x * A.e23.x : S.e23.x)
                             : (bR ? R.e23.x : 1.0);
    const double fe3c = acc0 ? (bA ? S.e23.y * A.e23.y : S.e23.y)
                             : (bR ? R.e23.y : 1.0);
    const double fd0c = acc0 ? (bA ? S.d01.x * A.d01.x : S.d01.x)
                             : (bR ? R.d01.x : 1.0);
    const double fd1c = acc0 ? (bA ? S.d01.y * A.d01.y : S.d01.y)
                             : (bR ? R.d01.y : 1.0);
    const double fd2c = acc0 ? (bA ? S.d23.x * A.d23.x : S.d23.x)
                             : (bR ? R.d23.x : 1.0);
    const double fd3c = acc0 ? (bA ? S.d23.y * A.d23.y : S.d23.y)
                             : (bR ? R.d23.y : 1.0);
    e0 *= fe0c; e1 *= fe1c; e2 *= fe2c; e3 *= fe3c;
    d0 *= fd0c; d1 *= fd1c; d2 *= fd2c; d3 *= fd3c;
    Dd = acc0 ? (bA ? PQA : PQ0) : (bR ? PQR : Dd);

    // w update: apply step s0 (precomputed wp), then step s1
    w0 = acc0 ? wp0 : w0;  w1 = acc0 ? wp1 : w1;  w2 = acc0 ? wp2 : w2;
    const unsigned sh1 = 2u * (site1 & 15u);
    const unsigned mb1 = 3u << sh1, nv1 = nc1 << sh1;
    const bool j0 = site1 < 16u, j1 = (site1 >= 16u) & (site1 < 32u);
    w0 = (acc1 && j0) ? ((w0 & ~mb1) | nv1) : w0;
    w1 = (acc1 && j1) ? ((w1 & ~mb1) | nv1) : w1;
    w2 = (acc1 && !(j0 || j1)) ? ((w2 & ~mb1) | nv1) : w2;
  }

  // ---- write one-hot output ----
  float4* o = (float4*)(out + (size_t)n * (kL * 4));
#pragma unroll
  for (int l = 0; l < kL; ++l) {
    const unsigned c = catAt(w0, w1, w2, (unsigned)l);
    o[l] = make_float4(c == 0u ? 1.0f : 0.0f, c == 1u ? 1.0f : 0.0f,
                       c == 2u ? 1.0f : 0.0f, c == 3u ? 1.0f : 0.0f);
  }
}

// ---------------- fallback (small ws): self-contained kernel (r5 form) ------
__device__ __forceinline__ void build_selB(const void* selp, double (*sB)[4]) {
  const unsigned* wp = (const unsigned*)selp;
  int mode;
  if (wp[0] == 0x3F800000u) mode = 0;
  else {
    mode = 1;
    for (int i = 0; i < kR * kM; ++i) if (wp[i] > 1u) { mode = 2; break; }
  }
  for (int r = 0; r < kR; ++r)
    for (int m = 0; m < kM; ++m) {
      const int i = r * 4 + m;
      unsigned b;
      if (mode == 0)      b = (wp[i] == 0x3F800000u) ? 1u : 0u;
      else if (mode == 1) b = wp[i] ? 1u : 0u;
      else                b = ((const unsigned char*)selp)[i] ? 1u : 0u;
      sB[r][m] = b ? 1.0 : 0.0;
    }
}

__global__ __launch_bounds__(64)
void mcmc_loop(const float* __restrict__ chains, const float* __restrict__ h0,
               const float* __restrict__ modes_h, const void* __restrict__ selp,
               float* __restrict__ out) {
  __shared__ double2 sEH[kL][4];
  __shared__ double2 sEM[kM][kL][4];
  __shared__ double  sFH[kL][16];
  __shared__ double2 sFM[kM][kL][16];
  __shared__ unsigned sSite[64];
  __shared__ uint2 sCK[64], sAK[64];
  __shared__ double sB[kR][4];

  const int tid = threadIdx.x;
  for (int i = tid; i < kL * 4; i += 64) {
    const double v = (double)h0[i];
    sEH[i >> 2][i & 3] = make_double2(exp(v), exp(-v));
  }
  for (int i = tid; i < kM * kL * 4; i += 64) {
    const double v = (double)modes_h[i];
    sEM[i / (kL * 4)][(i >> 2) % kL][i & 3] = make_double2(exp(v), exp(-v));
  }
  {
    const unsigned s = (unsigned)tid;
    if (s < (unsigned)kSteps) {
      unsigned ka, kb;  tf2(0u, 42u, 0u, s, ka, kb);
      unsigned i0, i1, r0, r1, a0, a1;
      tf2(ka, kb, 0u, 0u, i0, i1);
      tf2(ka, kb, 0u, 1u, r0, r1);
      tf2(ka, kb, 0u, 2u, a0, a1);
      unsigned h1a, h1b, l1a, l1b;
      tf2(i0, i1, 0u, 0u, h1a, h1b);
      tf2(i0, i1, 0u, 1u, l1a, l1b);
      const unsigned hb = rb32(h1a, h1b, 0u);
      const unsigned lb = rb32(l1a, l1b, 0u);
      sSite[s] = ((hb % 48u) * 16u + (lb % 48u)) % 48u;
      unsigned c0, c1;  tf2(r0, r1, 0u, 1u, c0, c1);
      sCK[s] = make_uint2(c0, c1);
      sAK[s] = make_uint2(a0, a1);
    } else {
      sSite[s] = 0u; sCK[s] = make_uint2(0u, 0u); sAK[s] = make_uint2(0u, 0u);
    }
  }
  if (tid == 0) build_selB(selp, sB);
  __syncthreads();
  for (int i = tid; i < kL * 16; i += 64) {
    const int l = i >> 4, p = i & 15, nw = p >> 2, od = p & 3;
    sFH[l][p] = sEH[l][nw].x * sEH[l][od].y;
#pragma unroll
    for (int m = 0; m < kM; ++m)
      sFM[m][l][p] = make_double2(sEM[m][l][nw].x * sEM[m][l][od].y,
                                  sEM[m][l][nw].y * sEM[m][l][od].x);
  }
  __syncthreads();

  const int n = blockIdx.x * 64 + tid;
  double bb[kR][4];
#pragma unroll
  for (int r = 0; r < kR; ++r)
#pragma unroll
    for (int m = 0; m < 4; ++m) bb[r][m] = sB[r][m];

  unsigned w0 = 0, w1 = 0, w2 = 0;
  {
    const float4* ch = (const float4*)(chains + (size_t)n * (kL * 4));
#pragma unroll
    for (int l = 0; l < kL; ++l) {
      const float4 v = ch[l];
      const unsigned c = (v.y > 0.5f) ? 1u : ((v.z > 0.5f) ? 2u : ((v.w > 0.5f) ? 3u : 0u));
      const unsigned sh = 2u * (unsigned)(l & 15);
      if (l < 16) w0 |= c << sh; else if (l < 32) w1 |= c << sh; else w2 |= c << sh;
    }
  }
  double e0 = 1.0, e1 = 1.0, e2 = 1.0, e3 = 1.0;
  double d0 = 1.0, d1 = 1.0, d2 = 1.0, d3 = 1.0;
#pragma unroll 4
  for (int l = 0; l < kL; ++l) {
    const unsigned c = catAt(w0, w1, w2, (unsigned)l);
    const double2 t0 = sEM[0][l][c], t1 = sEM[1][l][c];
    const double2 t2 = sEM[2][l][c], t3 = sEM[3][l][c];
    e0 *= t0.x; d0 *= t0.y;  e1 *= t1.x; d1 *= t1.y;
    e2 *= t2.x; d2 *= t2.y;  e3 *= t3.x; d3 *= t3.y;
  }
  double Dd = pow7((d0 + d1) + (d2 + d3));
#pragma unroll
  for (int r = 0; r < kR; ++r)
    Dd *= (fma(bb[r][1], e1, bb[r][0] * e0) + fma(bb[r][3], e3, bb[r][2] * e2));

  unsigned dw_c, dw_n;
  { const uint2 c0 = sCK[0], a0 = sAK[0];
    dw_c = (rb32(a0.x, a0.y, (unsigned)n) & 0xFFFFFE00u) |
           (rb32(c0.x, c0.y, (unsigned)n) & 3u); }
  { const uint2 c1 = sCK[1], a1 = sAK[1];
    dw_n = (rb32(a1.x, a1.y, (unsigned)n) & 0xFFFFFE00u) |
           (rb32(c1.x, c1.y, (unsigned)n) & 3u); }

  unsigned site_c = sSite[0];
  unsigned nc_c = dw_c & 3u;
  double fh_c;  double2 fm_c[4];
  {
    const unsigned idx = nc_c * 4u + catAt(w0, w1, w2, site_c);
    fh_c = sFH[site_c][idx];
#pragma unroll
    for (int m = 0; m < 4; ++m) fm_c[m] = sFM[m][site_c][idx];
  }

  for (int s = 0; s < kSteps; ++s) {
    const uint2 c2 = sCK[s + 2], a2 = sAK[s + 2];
    const unsigned dw_f = (rb32(a2.x, a2.y, (unsigned)n) & 0xFFFFFE00u) |
                          (rb32(c2.x, c2.y, (unsigned)n) & 3u);
    const unsigned site_n = sSite[s + 1];
    const unsigned nc_n = dw_n & 3u;
    const unsigned oldc_n = catAt(w0, w1, w2, site_n);
    double fh_n = sFH[site_n][nc_n * 4u + oldc_n];
    double2 fm_n[4];
#pragma unroll
    for (int m = 0; m < 4; ++m) fm_n[m] = sFM[m][site_n][nc_n * 4u + oldc_n];

    const float rndf = __uint_as_float((dw_c >> 9) | 0x3F800000u) - 1.0f;
    const double f0 = e0 * fm_c[0].x, g0 = d0 * fm_c[0].y;
    const double f1 = e1 * fm_c[1].x, g1 = d1 * fm_c[1].y;
    const double f2 = e2 * fm_c[2].x, g2 = d2 * fm_c[2].y;
    const double f3 = e3 * fm_c[3].x, g3 = d3 * fm_c[3].y;
    double se[kR];
#pragma unroll
    for (int r = 0; r < kR; ++r)
      se[r] = fma(bb[r][1], f1, bb[r][0] * f0) + fma(bb[r][3], f3, bb[r][2] * f2);
    const double PQ = (pow7((g0 + g1) + (g2 + g3)) *
                       ((se[0] * se[1]) * (se[2] * se[3]))) *
                      ((se[4] * se[5]) * se[6]);
    const double N = fh_c * PQ;
    const bool acc = N > (double)rndf * Dd;

    const unsigned sh = 2u * (site_c & 15u);
    const unsigned mb = 3u << sh, nv = nc_c << sh;
    const bool in0 = site_c < 16u, in1 = (site_c >= 16u) & (site_c < 32u);
    w0 = (acc && in0) ? ((w0 & ~mb) | nv) : w0;
    w1 = (acc && in1) ? ((w1 & ~mb) | nv) : w1;
    w2 = (acc && !(in0 || in1)) ? ((w2 & ~mb) | nv) : w2;
    e0 = acc ? f0 : e0; e1 = acc ? f1 : e1; e2 = acc ? f2 : e2; e3 = acc ? f3 : e3;
    d0 = acc ? g0 : d0; d1 = acc ? g1 : d1; d2 = acc ? g2 : d2; d3 = acc ? g3 : d3;
    Dd = acc ? PQ : Dd;

    if (site_n == site_c) {
      const unsigned to = acc ? nc_c : oldc_n;
      const unsigned i2 = nc_n * 4u + to;
      fh_n = sFH[site_n][i2];
#pragma unroll
      for (int m = 0; m < 4; ++m) fm_n[m] = sFM[m][site_n][i2];
    }
    site_c = site_n; nc_c = nc_n; dw_c = dw_n; dw_n = dw_f;
    fh_c = fh_n;
#pragma unroll
    for (int m = 0; m < 4; ++m) fm_c[m] = fm_n[m];
  }

  float4* o = (float4*)(out + (size_t)n * (kL * 4));
#pragma unroll
  for (int l = 0; l < kL; ++l) {
    const unsigned c = catAt(w0, w1, w2, (unsigned)l);
    o[l] = make_float4(c == 0u ? 1.0f : 0.0f, c == 1u ? 1.0f : 0.0f,
                       c == 2u ? 1.0f : 0.0f, c == 3u ? 1.0f : 0.0f);
  }
}

extern "C" void kernel_launch(void* const* d_in, const int* in_sizes, int n_in,
                              void* d_out, int out_size, void* d_ws, size_t ws_size,
                              hipStream_t stream) {
  const float* chains  = (const float*)d_in[0];
  const float* h0      = (const float*)d_in[1];
  const float* modes_h = (const float*)d_in[2];
  const void*  sel     = d_in[3];
  (void)in_sizes; (void)n_in; (void)out_size;

  const size_t need = (size_t)DRAWS_OFF + (size_t)kSteps * kN * sizeof(unsigned);
  if (ws_size >= need) {
    unsigned char* ws = (unsigned char*)d_ws;
    draw_kernel<<<dim3(kN / 256, kSteps + 1), dim3(256), 0, stream>>>(
        h0, modes_h, sel, ws);
    mcmc_spec<<<dim3(kN / 64), dim3(64), 0, stream>>>(chains, ws, (float*)d_out);
  } else {
    mcmc_loop<<<dim3(kN / 64), dim3(64), 0, stream>>>(
        chains, h0, modes_h, sel, (float*)d_out);
  }
}

// Round 13
// 69.738 us; speedup vs baseline: 1.1245x; 1.1245x over previous
//
#include <hip/hip_runtime.h>
#include <math.h>

// ---------------------------------------------------------------------------
// MultiRoundDistribution MCMC — bit-exact JAX PRNG (partitionable threefry).
// Round 13: instruction-count minimization (empirical law r2-r12: wall ~
// per-wave emitted instructions x ~15cy, invariant to dep structure).
//  - fma-form se (28 inst, the r5-r9 passing form) instead of select-form
//  - all wave-uniform step metadata (sites, rowbases, shifts, word-select,
//    draw keys) computed ON HOST (bit-identical threefry) -> kernel args
//    (SGPR/SMEM, zero VALU)
//  - no pipeline/speculation machinery: lean ~95-inst step body
//  - draw_kernel = draws only; tables built by a 1-block table_kernel
// N=16384 chains, 1 thread/chain, 256 blocks x 64 threads.
// ---------------------------------------------------------------------------

constexpr int kN = 16384;
constexpr int kL = 48;
constexpr int kM = 4;
constexpr int kR = 7;
constexpr int kSteps = 48;  // n_sweeps(=1) * L

// ---- d_ws layout (ROWS/SING/BB identical to rounds 7-12) ----
constexpr int ROWS_OFF = 0;                       // 768 rows x 80B (site*1280 + nc*320 + oldc*80)
constexpr int SING_OFF = 61440;                   // 48*4 x 64B (exp singles)
constexpr int BB_OFF   = 74128;                   // 21 doubles (b1,b2,b3 per round)
constexpr int TAB_BYTES = 74752;
constexpr int DRAWS_OFF = 74752;                  // 48*16384 u32

struct StepMeta {
  unsigned rowbase[kSteps];   // site*1280
  unsigned shamt[kSteps];     // 2*(site&15)
  unsigned widx[kSteps];      // 0/1/2 which packed word
  unsigned keys[kSteps][4];   // c0,c1,a0,a1 per step
};

// ---------------- Threefry-2x32 (JAX rotation schedule), host+device -------
#define TF_ROUND(rot) do { x0 += x1; x1 = (x1 << (rot)) | (x1 >> (32 - (rot))); x1 ^= x0; } while (0)

__host__ __device__ __forceinline__ void tf2(unsigned ka, unsigned kb,
                                             unsigned x0, unsigned x1,
                                             unsigned& o0, unsigned& o1) {
  const unsigned ks2 = ka ^ kb ^ 0x1BD11BDAu;
  x0 += ka; x1 += kb;
  TF_ROUND(13); TF_ROUND(15); TF_ROUND(26); TF_ROUND(6);
  x0 += kb; x1 += ks2 + 1u;
  TF_ROUND(17); TF_ROUND(29); TF_ROUND(16); TF_ROUND(24);
  x0 += ks2; x1 += ka + 2u;
  TF_ROUND(13); TF_ROUND(15); TF_ROUND(26); TF_ROUND(6);
  x0 += ka; x1 += kb + 3u;
  TF_ROUND(17); TF_ROUND(29); TF_ROUND(16); TF_ROUND(24);
  x0 += kb; x1 += ks2 + 4u;
  TF_ROUND(13); TF_ROUND(15); TF_ROUND(26); TF_ROUND(6);
  x0 += ks2; x1 += ka + 5u;
  o0 = x0; o1 = x1;
}

__host__ __device__ __forceinline__ unsigned rb32(unsigned ka, unsigned kb, unsigned i) {
  unsigned o0, o1; tf2(ka, kb, 0u, i, o0, o1); return o0 ^ o1;
}

__device__ __forceinline__ double pow7(double x) {
  const double x2 = x * x, x4 = x2 * x2;
  return x4 * x2 * x;
}

__device__ __forceinline__ unsigned catAt(unsigned w0, unsigned w1, unsigned w2,
                                          unsigned site) {
  const unsigned ww = (site < 16u) ? w0 : ((site < 32u) ? w1 : w2);
  return (ww >> (2u * (site & 15u))) & 3u;
}

// ---------------- phase 1a: draws only (keys from args) ----------------
__global__ __launch_bounds__(256)
void draw_kernel(StepMeta P, unsigned char* __restrict__ ws) {
  const unsigned s = blockIdx.y;
  const unsigned n = blockIdx.x * 256u + threadIdx.x;
  const unsigned nc = rb32(P.keys[s][0], P.keys[s][1], n) & 3u;
  const unsigned ub = rb32(P.keys[s][2], P.keys[s][3], n);
  ((unsigned*)(ws + DRAWS_OFF))[s * (unsigned)kN + n] = (ub & 0xFFFFFE00u) | nc;
}

// ---------------- phase 1b: tables (1 block) ----------------
__global__ __launch_bounds__(256)
void table_kernel(const float* __restrict__ h0, const float* __restrict__ modes_h,
                  const void* __restrict__ selp, unsigned char* __restrict__ ws) {
  __shared__ double exl[kL][5][4][2];   // [l][field: h,m0..3][cat][{+,-}]
  const unsigned t = threadIdx.x;

  if (t < 240u) {
    const int l = t / 5, k = t % 5;
#pragma unroll
    for (int c = 0; c < 4; ++c) {
      const double v = (k == 0) ? (double)h0[l * 4 + c]
                                : (double)modes_h[((k - 1) * kL + l) * 4 + c];
      exl[l][k][c][0] = exp(v);
      exl[l][k][c][1] = exp(-v);
    }
  }
  if (t == 255u) {
    const unsigned* wp = (const unsigned*)selp;
    int mode;
    if (wp[0] == 0x3F800000u) mode = 0;
    else {
      mode = 1;
      for (int i = 0; i < kR * kM; ++i) if (wp[i] > 1u) { mode = 2; break; }
    }
    double* bbw = (double*)(ws + BB_OFF);
    for (int r = 0; r < kR; ++r)
      for (int m = 1; m < kM; ++m) {
        const int i = r * 4 + m;
        unsigned b;
        if (mode == 0)      b = (wp[i] == 0x3F800000u) ? 1u : 0u;
        else if (mode == 1) b = wp[i] ? 1u : 0u;
        else                b = ((const unsigned char*)selp)[i] ? 1u : 0u;
        bbw[r * 3 + (m - 1)] = b ? 1.0 : 0.0;
      }
  }
  __syncthreads();

  for (int R = t; R < kL * 16; R += 256) {
    const int l = R >> 4, idx = R & 15, nw = idx >> 2, od = idx & 3;
    double* row = (double*)(ws + ROWS_OFF + (size_t)R * 80);
#pragma unroll
    for (int m = 0; m < 4; ++m) {
      row[m]     = exl[l][1 + m][nw][0] * exl[l][1 + m][od][1];  // fe_m
      row[4 + m] = exl[l][1 + m][nw][1] * exl[l][1 + m][od][0];  // fd_m
    }
    row[8] = exl[l][0][nw][0] * exl[l][0][od][1];                // fh
    row[9] = 0.0;
  }
  if (t < 192u) {
    const int l = t >> 2, c = t & 3;
    double* sg = (double*)(ws + SING_OFF + (size_t)(l * 4 + c) * 64);
#pragma unroll
    for (int m = 0; m < 4; ++m) {
      sg[2 * m]     = exl[l][1 + m][c][0];
      sg[2 * m + 1] = exl[l][1 + m][c][1];
    }
  }
}

// ---------------- phase 2: lean MCMC ----------------
__global__ __launch_bounds__(64)
void mcmc_lean(const float* __restrict__ chains, const unsigned char* __restrict__ ws,
               StepMeta P, float* __restrict__ out) {
  __shared__ __align__(16) char sTab[TAB_BYTES];
  __shared__ unsigned sDraws[kSteps * 64];

  const int tid = threadIdx.x;
  const int n = blockIdx.x * 64 + tid;

  // ---- stage tables + draws into LDS ----
  {
    const float4* gt = (const float4*)(ws + ROWS_OFF);
    float4* lt = (float4*)sTab;
    for (int i = tid; i < TAB_BYTES / 16; i += 64) lt[i] = gt[i];
    const unsigned* gd = (const unsigned*)(ws + DRAWS_OFF);
    for (int s = 0; s < kSteps; ++s)
      sDraws[s * 64 + tid] = gd[(size_t)s * kN + n];
  }

  // ---- decode chain state (overlaps staging latency) ----
  unsigned w0 = 0, w1 = 0, w2 = 0;
  {
    const float4* ch = (const float4*)(chains + (size_t)n * (kL * 4));
#pragma unroll
    for (int l = 0; l < kL; ++l) {
      const float4 v = ch[l];
      const unsigned c = (v.y > 0.5f) ? 1u : ((v.z > 0.5f) ? 2u : ((v.w > 0.5f) ? 3u : 0u));
      const unsigned sh = 2u * (unsigned)(l & 15);
      if (l < 16) w0 |= c << sh; else if (l < 32) w1 |= c << sh; else w2 |= c << sh;
    }
  }
  __syncthreads();

  // ---- selection weights (b0 == 1 by construction) ----
  double b1[kR], b2[kR], b3[kR];
  {
    const double* bbw = (const double*)(sTab + BB_OFF);
#pragma unroll
    for (int r = 0; r < kR; ++r) {
      b1[r] = bbw[r * 3 + 0];
      b2[r] = bbw[r * 3 + 1];
      b3[r] = bbw[r * 3 + 2];
    }
  }

  // ---- initial multiplicative state from singles ----
  double e0 = 1.0, e1 = 1.0, e2 = 1.0, e3 = 1.0;
  double d0 = 1.0, d1 = 1.0, d2 = 1.0, d3 = 1.0;
#pragma unroll 4
  for (int l = 0; l < kL; ++l) {
    const unsigned c = catAt(w0, w1, w2, (unsigned)l);
    const double* sg = (const double*)(sTab + SING_OFF + (size_t)(l * 4 + c) * 64);
    e0 *= sg[0]; d0 *= sg[1];  e1 *= sg[2]; d1 *= sg[3];
    e2 *= sg[4]; d2 *= sg[5];  e3 *= sg[6]; d3 *= sg[7];
  }
  double Dd = pow7((d0 + d1) + (d2 + d3));
#pragma unroll
  for (int r = 0; r < kR; ++r)
    Dd *= (fma(b1[r], e1, e0) + fma(b3[r], e3, b2[r] * e2));

  // ---- 48 lean steps; all wave-uniform metadata from kernel args (SMEM) ----
  for (int s = 0; s < kSteps; ++s) {
    const unsigned rowb = P.rowbase[s];      // scalar loads, zero VALU
    const unsigned sh = P.shamt[s];
    const unsigned wi = P.widx[s];
    const unsigned dw = sDraws[s * 64 + tid];

    const unsigned ww = (wi == 0u) ? w0 : ((wi == 1u) ? w1 : w2);
    const unsigned oldc = (ww >> sh) & 3u;
    const char* rb = sTab + rowb + (dw & 3u) * 320u + oldc * 80u;
    const double2 fe01 = *(const double2*)(rb);
    const double2 fe23 = *(const double2*)(rb + 16);
    const double2 fd01 = *(const double2*)(rb + 32);
    const double2 fd23 = *(const double2*)(rb + 48);
    const double fh    = *(const double*)(rb + 64);

    const float rndf = __uint_as_float((dw >> 9) | 0x3F800000u) - 1.0f;
    const double f0 = e0 * fe01.x, f1 = e1 * fe01.y;
    const double f2 = e2 * fe23.x, f3 = e3 * fe23.y;
    const double g0 = d0 * fd01.x, g1 = d1 * fd01.y;
    const double g2 = d2 * fd23.x, g3 = d3 * fd23.y;
    double se[kR];
#pragma unroll
    for (int r = 0; r < kR; ++r)
      se[r] = fma(b1[r], f1, f0) + fma(b3[r], f3, b2[r] * f2);
    const double PQ = (pow7((g0 + g1) + (g2 + g3)) *
                       ((se[0] * se[1]) * (se[2] * se[3]))) *
                      ((se[4] * se[5]) * se[6]);
    const double N = fh * PQ;
    const bool acc = N > (double)rndf * Dd;

    const unsigned nc = dw & 3u;
    const unsigned mb = 3u << sh, nv = nc << sh;
    const unsigned wnew = (ww & ~mb) | nv;
    w0 = (acc && wi == 0u) ? wnew : w0;
    w1 = (acc && wi == 1u) ? wnew : w1;
    w2 = (acc && wi == 2u) ? wnew : w2;
    e0 = acc ? f0 : e0; e1 = acc ? f1 : e1; e2 = acc ? f2 : e2; e3 = acc ? f3 : e3;
    d0 = acc ? g0 : d0; d1 = acc ? g1 : d1; d2 = acc ? g2 : d2; d3 = acc ? g3 : d3;
    Dd = acc ? PQ : Dd;
  }

  // ---- write one-hot output ----
  float4* o = (float4*)(out + (size_t)n * (kL * 4));
#pragma unroll
  for (int l = 0; l < kL; ++l) {
    const unsigned c = catAt(w0, w1, w2, (unsigned)l);
    o[l] = make_float4(c == 0u ? 1.0f : 0.0f, c == 1u ? 1.0f : 0.0f,
                       c == 2u ? 1.0f : 0.0f, c == 3u ? 1.0f : 0.0f);
  }
}

// ---------------- fallback (small ws): self-contained kernel ----------------
__device__ __forceinline__ void build_selB(const void* selp, double (*sB)[4]) {
  const unsigned* wp = (const unsigned*)selp;
  int mode;
  if (wp[0] == 0x3F800000u) mode = 0;
  else {
    mode = 1;
    for (int i = 0; i < kR * kM; ++i) if (wp[i] > 1u) { mode = 2; break; }
  }
  for (int r = 0; r < kR; ++r)
    for (int m = 0; m < kM; ++m) {
      const int i = r * 4 + m;
      unsigned b;
      if (mode == 0)      b = (wp[i] == 0x3F800000u) ? 1u : 0u;
      else if (mode == 1) b = wp[i] ? 1u : 0u;
      else                b = ((const unsigned char*)selp)[i] ? 1u : 0u;
      sB[r][m] = b ? 1.0 : 0.0;
    }
}

__global__ __launch_bounds__(64)
void mcmc_loop(const float* __restrict__ chains, const float* __restrict__ h0,
               const float* __restrict__ modes_h, const void* __restrict__ selp,
               StepMeta P, float* __restrict__ out) {
  __shared__ double2 sEM[kM][kL][4];
  __shared__ double2 sEH[kL][4];
  __shared__ double  sFH[kL][16];
  __shared__ double2 sFM[kM][kL][16];
  __shared__ double sB[kR][4];

  const int tid = threadIdx.x;
  for (int i = tid; i < kL * 4; i += 64) {
    const double v = (double)h0[i];
    sEH[i >> 2][i & 3] = make_double2(exp(v), exp(-v));
  }
  for (int i = tid; i < kM * kL * 4; i += 64) {
    const double v = (double)modes_h[i];
    sEM[i / (kL * 4)][(i >> 2) % kL][i & 3] = make_double2(exp(v), exp(-v));
  }
  if (tid == 0) build_selB(selp, sB);
  __syncthreads();
  for (int i = tid; i < kL * 16; i += 64) {
    const int l = i >> 4, p = i & 15, nw = p >> 2, od = p & 3;
    sFH[l][p] = sEH[l][nw].x * sEH[l][od].y;
#pragma unroll
    for (int m = 0; m < kM; ++m)
      sFM[m][l][p] = make_double2(sEM[m][l][nw].x * sEM[m][l][od].y,
                                  sEM[m][l][nw].y * sEM[m][l][od].x);
  }
  __syncthreads();

  const int n = blockIdx.x * 64 + tid;
  double bb[kR][4];
#pragma unroll
  for (int r = 0; r < kR; ++r)
#pragma unroll
    for (int m = 0; m < 4; ++m) bb[r][m] = sB[r][m];

  unsigned w0 = 0, w1 = 0, w2 = 0;
  {
    const float4* ch = (const float4*)(chains + (size_t)n * (kL * 4));
#pragma unroll
    for (int l = 0; l < kL; ++l) {
      const float4 v = ch[l];
      const unsigned c = (v.y > 0.5f) ? 1u : ((v.z > 0.5f) ? 2u : ((v.w > 0.5f) ? 3u : 0u));
      const unsigned sh = 2u * (unsigned)(l & 15);
      if (l < 16) w0 |= c << sh; else if (l < 32) w1 |= c << sh; else w2 |= c << sh;
    }
  }
  double e0 = 1.0, e1 = 1.0, e2 = 1.0, e3 = 1.0;
  double d0 = 1.0, d1 = 1.0, d2 = 1.0, d3 = 1.0;
#pragma unroll 4
  for (int l = 0; l < kL; ++l) {
    const unsigned c = catAt(w0, w1, w2, (unsigned)l);
    const double2 t0 = sEM[0][l][c], t1 = sEM[1][l][c];
    const double2 t2 = sEM[2][l][c], t3 = sEM[3][l][c];
    e0 *= t0.x; d0 *= t0.y;  e1 *= t1.x; d1 *= t1.y;
    e2 *= t2.x; d2 *= t2.y;  e3 *= t3.x; d3 *= t3.y;
  }
  double Dd = pow7((d0 + d1) + (d2 + d3));
#pragma unroll
  for (int r = 0; r < kR; ++r)
    Dd *= (fma(bb[r][1], e1, bb[r][0] * e0) + fma(bb[r][3], e3, bb[r][2] * e2));

  for (int s = 0; s < kSteps; ++s) {
    const unsigned sh = P.shamt[s], wi = P.widx[s];
    const unsigned site = (P.rowbase[s] / 1280u);
    const unsigned dw = (rb32(P.keys[s][2], P.keys[s][3], (unsigned)n) & 0xFFFFFE00u) |
                        (rb32(P.keys[s][0], P.keys[s][1], (unsigned)n) & 3u);
    const unsigned nc = dw & 3u;
    const unsigned ww = (wi == 0u) ? w0 : ((wi == 1u) ? w1 : w2);
    const unsigned oldc = (ww >> sh) & 3u;
    const unsigned idx = nc * 4u + oldc;
    const double fh_c = sFH[site][idx];
    const double2 fm0 = sFM[0][site][idx], fm1 = sFM[1][site][idx];
    const double2 fm2 = sFM[2][site][idx], fm3 = sFM[3][site][idx];

    const float rndf = __uint_as_float((dw >> 9) | 0x3F800000u) - 1.0f;
    const double f0 = e0 * fm0.x, g0 = d0 * fm0.y;
    const double f1 = e1 * fm1.x, g1 = d1 * fm1.y;
    const double f2 = e2 * fm2.x, g2 = d2 * fm2.y;
    const double f3 = e3 * fm3.x, g3 = d3 * fm3.y;
    double se[kR];
#pragma unroll
    for (int r = 0; r < kR; ++r)
      se[r] = fma(bb[r][1], f1, bb[r][0] * f0) + fma(bb[r][3], f3, bb[r][2] * f2);
    const double PQ = (pow7((g0 + g1) + (g2 + g3)) *
                       ((se[0] * se[1]) * (se[2] * se[3]))) *
                      ((se[4] * se[5]) * se[6]);
    const double N = fh_c * PQ;
    const bool acc = N > (double)rndf * Dd;

    const unsigned mb = 3u << sh, nv = nc << sh;
    const unsigned wnew = (ww & ~mb) | nv;
    w0 = (acc && wi == 0u) ? wnew : w0;
    w1 = (acc && wi == 1u) ? wnew : w1;
    w2 = (acc && wi == 2u) ? wnew : w2;
    e0 = acc ? f0 : e0; e1 = acc ? f1 : e1; e2 = acc ? f2 : e2; e3 = acc ? f3 : e3;
    d0 = acc ? g0 : d0; d1 = acc ? g1 : d1; d2 = acc ? g2 : d2; d3 = acc ? g3 : d3;
    Dd = acc ? PQ : Dd;
  }

  float4* o = (float4*)(out + (size_t)n * (kL * 4));
#pragma unroll
  for (int l = 0; l < kL; ++l) {
    const unsigned c = catAt(w0, w1, w2, (unsigned)l);
    o[l] = make_float4(c == 0u ? 1.0f : 0.0f, c == 1u ? 1.0f : 0.0f,
                       c == 2u ? 1.0f : 0.0f, c == 3u ? 1.0f : 0.0f);
  }
}

extern "C" void kernel_launch(void* const* d_in, const int* in_sizes, int n_in,
                              void* d_out, int out_size, void* d_ws, size_t ws_size,
                              hipStream_t stream) {
  const float* chains  = (const float*)d_in[0];
  const float* h0      = (const float*)d_in[1];
  const float* modes_h = (const float*)d_in[2];
  const void*  sel     = d_in[3];
  (void)in_sizes; (void)n_in; (void)out_size;

  // ---- host-side wave-uniform PRNG metadata (bit-identical threefry) ----
  StepMeta P;
  for (unsigned s = 0; s < (unsigned)kSteps; ++s) {
    unsigned ka, kb, i0, i1, r0, r1, a0, a1, c0, c1;
    tf2(0u, 42u, 0u, s, ka, kb);                            // split(key(42),48)[s]
    tf2(ka, kb, 0u, 0u, i0, i1);                            // k_idx
    tf2(ka, kb, 0u, 1u, r0, r1);                            // k_res
    tf2(ka, kb, 0u, 2u, a0, a1);                            // k_acc
    unsigned h1a, h1b, l1a, l1b;
    tf2(i0, i1, 0u, 0u, h1a, h1b);
    tf2(i0, i1, 0u, 1u, l1a, l1b);
    const unsigned hb = rb32(h1a, h1b, 0u);
    const unsigned lb = rb32(l1a, l1b, 0u);
    const unsigned site = ((hb % 48u) * 16u + (lb % 48u)) % 48u;
    tf2(r0, r1, 0u, 1u, c0, c1);                            // k2 of split(k_res,2)
    P.rowbase[s] = site * 1280u;
    P.shamt[s]   = 2u * (site & 15u);
    P.widx[s]    = (site < 16u) ? 0u : ((site < 32u) ? 1u : 2u);
    P.keys[s][0] = c0; P.keys[s][1] = c1; P.keys[s][2] = a0; P.keys[s][3] = a1;
  }

  const size_t need = (size_t)DRAWS_OFF + (size_t)kSteps * kN * sizeof(unsigned);
  if (ws_size >= need) {
    unsigned char* ws = (unsigned char*)d_ws;
    draw_kernel<<<dim3(kN / 256, kSteps), dim3(256), 0, stream>>>(P, ws);
    table_kernel<<<dim3(1), dim3(256), 0, stream>>>(h0, modes_h, sel, ws);
    mcmc_lean<<<dim3(kN / 64), dim3(64), 0, stream>>>(chains, ws, P, (float*)d_out);
  } else {
    mcmc_loop<<<dim3(kN / 64), dim3(64), 0, stream>>>(
        chains, h0, modes_h, sel, P, (float*)d_out);
  }
}

// Round 14
// 48.609 us; speedup vs baseline: 1.6132x; 1.4347x over previous
//
#include <hip/hip_runtime.h>
#include <math.h>

// ---------------------------------------------------------------------------
// MultiRoundDistribution MCMC — bit-exact JAX PRNG (partitionable threefry).
// Round 14: best-of consolidation.
//   - r6's full 48-step unroll (only variant measured below 1.05us/step)
//     with tables built in-kernel (best-measured total structure)
//   - r13's host-computed StepMeta (sites/shifts/rowbases/draw keys as
//     kernel args -> SGPRs; zero in-kernel wave-uniform PRNG)
//   - draws staged to LDS, read at static offsets (r6's reg-preload spilled)
//   - r13's lean fma-form step body (fewest-instruction passing form)
// N=16384 chains, 1 thread/chain, 256 blocks x 64 threads.
// ---------------------------------------------------------------------------

constexpr int kN = 16384;
constexpr int kL = 48;
constexpr int kM = 4;
constexpr int kR = 7;
constexpr int kSteps = 48;  // n_sweeps(=1) * L

struct StepMeta {
  unsigned rowbase[kSteps];   // site*1280 (byte offset into row table)
  unsigned shamt[kSteps];     // 2*(site&15)
  unsigned widx[kSteps];      // 0/1/2: which packed state word
  unsigned keys[kSteps][4];   // c0,c1,a0,a1 per step
};

// ---------------- Threefry-2x32 (JAX rotation schedule), host+device -------
#define TF_ROUND(rot) do { x0 += x1; x1 = (x1 << (rot)) | (x1 >> (32 - (rot))); x1 ^= x0; } while (0)

__host__ __device__ __forceinline__ void tf2(unsigned ka, unsigned kb,
                                             unsigned x0, unsigned x1,
                                             unsigned& o0, unsigned& o1) {
  const unsigned ks2 = ka ^ kb ^ 0x1BD11BDAu;
  x0 += ka; x1 += kb;
  TF_ROUND(13); TF_ROUND(15); TF_ROUND(26); TF_ROUND(6);
  x0 += kb; x1 += ks2 + 1u;
  TF_ROUND(17); TF_ROUND(29); TF_ROUND(16); TF_ROUND(24);
  x0 += ks2; x1 += ka + 2u;
  TF_ROUND(13); TF_ROUND(15); TF_ROUND(26); TF_ROUND(6);
  x0 += ka; x1 += kb + 3u;
  TF_ROUND(17); TF_ROUND(29); TF_ROUND(16); TF_ROUND(24);
  x0 += kb; x1 += ks2 + 4u;
  TF_ROUND(13); TF_ROUND(15); TF_ROUND(26); TF_ROUND(6);
  x0 += ks2; x1 += ka + 5u;
  o0 = x0; o1 = x1;
}

__host__ __device__ __forceinline__ unsigned rb32(unsigned ka, unsigned kb, unsigned i) {
  unsigned o0, o1; tf2(ka, kb, 0u, i, o0, o1); return o0 ^ o1;
}

__device__ __forceinline__ double pow7(double x) {
  const double x2 = x * x, x4 = x2 * x2;
  return x4 * x2 * x;
}

__device__ __forceinline__ unsigned catAt(unsigned w0, unsigned w1, unsigned w2,
                                          unsigned site) {
  const unsigned ww = (site < 16u) ? w0 : ((site < 32u) ? w1 : w2);
  return (ww >> (2u * (site & 15u))) & 3u;
}

// ---------------- phase 1: draws only (keys from host args) ----------------
__global__ __launch_bounds__(256)
void draw_kernel(StepMeta P, unsigned* __restrict__ draws) {
  const unsigned s = blockIdx.y;
  const unsigned n = blockIdx.x * 256u + threadIdx.x;
  const unsigned nc = rb32(P.keys[s][0], P.keys[s][1], n) & 3u;
  const unsigned ub = rb32(P.keys[s][2], P.keys[s][3], n);
  draws[s * (unsigned)kN + n] = (ub & 0xFFFFFE00u) | nc;
}

// ---------------- phase 2: fully-unrolled MCMC, in-kernel tables ----------
__global__ __launch_bounds__(64)
void mcmc_best(const float* __restrict__ chains, const float* __restrict__ h0,
               const float* __restrict__ modes_h, const void* __restrict__ selp,
               const unsigned* __restrict__ draws, StepMeta P,
               float* __restrict__ out) {
  __shared__ __align__(16) double sRows[kL * 16 * 10];   // 61440 B pair-factor rows
  __shared__ __align__(16) double sSing[kL * 4 * 8];     // 12288 B exp singles
  __shared__ double exl[kL][5][4][2];                    // 15360 B staging
  __shared__ double sBB[kR * 3];                         // b1,b2,b3 per round
  __shared__ unsigned sDraws[kSteps * 64];               // 12288 B

  const int tid = threadIdx.x;
  const int n = blockIdx.x * 64 + tid;

  // ---- stage this block's draws global -> LDS ----
  for (int s = 0; s < kSteps; ++s)
    sDraws[s * 64 + tid] = draws[(size_t)s * kN + n];

  // ---- decode chain state (overlaps staging latency) ----
  unsigned w0 = 0, w1 = 0, w2 = 0;
  {
    const float4* ch = (const float4*)(chains + (size_t)n * (kL * 4));
#pragma unroll
    for (int l = 0; l < kL; ++l) {
      const float4 v = ch[l];
      const unsigned c = (v.y > 0.5f) ? 1u : ((v.z > 0.5f) ? 2u : ((v.w > 0.5f) ? 3u : 0u));
      const unsigned sh = 2u * (unsigned)(l & 15);
      if (l < 16) w0 |= c << sh; else if (l < 32) w1 |= c << sh; else w2 |= c << sh;
    }
  }

  // ---- exp tables (setup-only transcendentals; 240 items over 64 lanes) ----
  for (int i = tid; i < kL * 5; i += 64) {
    const int l = i / 5, k = i % 5;
#pragma unroll
    for (int c = 0; c < 4; ++c) {
      const double v = (k == 0) ? (double)h0[l * 4 + c]
                                : (double)modes_h[((k - 1) * kL + l) * 4 + c];
      exl[l][k][c][0] = exp(v);
      exl[l][k][c][1] = exp(-v);
    }
  }
  if (tid == 0) {
    // selected_modes dtype detection (float32 / int32 / bool8); b0 always true.
    const unsigned* wp = (const unsigned*)selp;
    int mode;
    if (wp[0] == 0x3F800000u) mode = 0;
    else {
      mode = 1;
      for (int i = 0; i < kR * kM; ++i) if (wp[i] > 1u) { mode = 2; break; }
    }
    for (int r = 0; r < kR; ++r)
      for (int m = 1; m < kM; ++m) {
        const int i = r * 4 + m;
        unsigned b;
        if (mode == 0)      b = (wp[i] == 0x3F800000u) ? 1u : 0u;
        else if (mode == 1) b = wp[i] ? 1u : 0u;
        else                b = ((const unsigned char*)selp)[i] ? 1u : 0u;
        sBB[r * 3 + (m - 1)] = b ? 1.0 : 0.0;
      }
  }
  __syncthreads();

  // ---- pair-factor rows + singles (bit-identical products to r7-r13) ----
  for (int R = tid; R < kL * 16; R += 64) {
    const int l = R >> 4, idx = R & 15, nw = idx >> 2, od = idx & 3;
    double* row = sRows + (size_t)R * 10;
#pragma unroll
    for (int m = 0; m < 4; ++m) {
      row[m]     = exl[l][1 + m][nw][0] * exl[l][1 + m][od][1];  // fe_m
      row[4 + m] = exl[l][1 + m][nw][1] * exl[l][1 + m][od][0];  // fd_m
    }
    row[8] = exl[l][0][nw][0] * exl[l][0][od][1];                // fh
    row[9] = 0.0;
  }
  for (int i = tid; i < kL * 4; i += 64) {
    const int l = i >> 2, c = i & 3;
    double* sg = sSing + (size_t)i * 8;
#pragma unroll
    for (int m = 0; m < 4; ++m) {
      sg[2 * m]     = exl[l][1 + m][c][0];
      sg[2 * m + 1] = exl[l][1 + m][c][1];
    }
  }
  __syncthreads();

  // ---- selection weights (b0 == 1 by construction) ----
  double b1[kR], b2[kR], b3[kR];
#pragma unroll
  for (int r = 0; r < kR; ++r) {
    b1[r] = sBB[r * 3 + 0];
    b2[r] = sBB[r * 3 + 1];
    b3[r] = sBB[r * 3 + 2];
  }

  // ---- initial multiplicative state from singles ----
  double e0 = 1.0, e1 = 1.0, e2 = 1.0, e3 = 1.0;
  double d0 = 1.0, d1 = 1.0, d2 = 1.0, d3 = 1.0;
#pragma unroll 4
  for (int l = 0; l < kL; ++l) {
    const unsigned c = catAt(w0, w1, w2, (unsigned)l);
    const double* sg = sSing + (size_t)(l * 4 + c) * 8;
    e0 *= sg[0]; d0 *= sg[1];  e1 *= sg[2]; d1 *= sg[3];
    e2 *= sg[4]; d2 *= sg[5];  e3 *= sg[6]; d3 *= sg[7];
  }
  double Dd = pow7((d0 + d1) + (d2 + d3));
#pragma unroll
  for (int r = 0; r < kR; ++r)
    Dd *= (fma(b1[r], e1, e0) + fma(b3[r], e3, b2[r] * e2));

  // ---- 48 fully-unrolled lean steps; metadata from kernel args (SGPR) ----
#pragma unroll
  for (int s = 0; s < kSteps; ++s) {
    const unsigned rowb = P.rowbase[s];
    const unsigned sh = P.shamt[s];
    const unsigned wi = P.widx[s];
    const unsigned dw = sDraws[s * 64 + tid];      // static LDS offset

    const unsigned ww = (wi == 0u) ? w0 : ((wi == 1u) ? w1 : w2);
    const unsigned oldc = (ww >> sh) & 3u;
    const double* rb = (const double*)((const char*)sRows + rowb +
                                       (dw & 3u) * 320u + oldc * 80u);
    const double2 fe01 = *(const double2*)(rb);
    const double2 fe23 = *(const double2*)(rb + 2);
    const double2 fd01 = *(const double2*)(rb + 4);
    const double2 fd23 = *(const double2*)(rb + 6);
    const double fh    = rb[8];

    const float rndf = __uint_as_float((dw >> 9) | 0x3F800000u) - 1.0f;
    const double f0 = e0 * fe01.x, f1 = e1 * fe01.y;
    const double f2 = e2 * fe23.x, f3 = e3 * fe23.y;
    const double g0 = d0 * fd01.x, g1 = d1 * fd01.y;
    const double g2 = d2 * fd23.x, g3 = d3 * fd23.y;
    double se[kR];
#pragma unroll
    for (int r = 0; r < kR; ++r)
      se[r] = fma(b1[r], f1, f0) + fma(b3[r], f3, b2[r] * f2);
    const double PQ = (pow7((g0 + g1) + (g2 + g3)) *
                       ((se[0] * se[1]) * (se[2] * se[3]))) *
                      ((se[4] * se[5]) * se[6]);
    const double N = fh * PQ;
    const bool acc = N > (double)rndf * Dd;

    const unsigned nc = dw & 3u;
    const unsigned mb = 3u << sh, nv = nc << sh;
    const unsigned wnew = (ww & ~mb) | nv;
    w0 = (acc && wi == 0u) ? wnew : w0;
    w1 = (acc && wi == 1u) ? wnew : w1;
    w2 = (acc && wi == 2u) ? wnew : w2;
    e0 = acc ? f0 : e0; e1 = acc ? f1 : e1; e2 = acc ? f2 : e2; e3 = acc ? f3 : e3;
    d0 = acc ? g0 : d0; d1 = acc ? g1 : d1; d2 = acc ? g2 : d2; d3 = acc ? g3 : d3;
    Dd = acc ? PQ : Dd;
  }

  // ---- write one-hot output ----
  float4* o = (float4*)(out + (size_t)n * (kL * 4));
#pragma unroll
  for (int l = 0; l < kL; ++l) {
    const unsigned c = catAt(w0, w1, w2, (unsigned)l);
    o[l] = make_float4(c == 0u ? 1.0f : 0.0f, c == 1u ? 1.0f : 0.0f,
                       c == 2u ? 1.0f : 0.0f, c == 3u ? 1.0f : 0.0f);
  }
}

// ---------------- fallback (small ws): self-contained kernel (r13, passed) --
__device__ __forceinline__ void build_selB(const void* selp, double (*sB)[4]) {
  const unsigned* wp = (const unsigned*)selp;
  int mode;
  if (wp[0] == 0x3F800000u) mode = 0;
  else {
    mode = 1;
    for (int i = 0; i < kR * kM; ++i) if (wp[i] > 1u) { mode = 2; break; }
  }
  for (int r = 0; r < kR; ++r)
    for (int m = 0; m < kM; ++m) {
      const int i = r * 4 + m;
      unsigned b;
      if (mode == 0)      b = (wp[i] == 0x3F800000u) ? 1u : 0u;
      else if (mode == 1) b = wp[i] ? 1u : 0u;
      else                b = ((const unsigned char*)selp)[i] ? 1u : 0u;
      sB[r][m] = b ? 1.0 : 0.0;
    }
}

__global__ __launch_bounds__(64)
void mcmc_loop(const float* __restrict__ chains, const float* __restrict__ h0,
               const float* __restrict__ modes_h, const void* __restrict__ selp,
               StepMeta P, float* __restrict__ out) {
  __shared__ double2 sEM[kM][kL][4];
  __shared__ double2 sEH[kL][4];
  __shared__ double  sFH[kL][16];
  __shared__ double2 sFM[kM][kL][16];
  __shared__ double sB[kR][4];

  const int tid = threadIdx.x;
  for (int i = tid; i < kL * 4; i += 64) {
    const double v = (double)h0[i];
    sEH[i >> 2][i & 3] = make_double2(exp(v), exp(-v));
  }
  for (int i = tid; i < kM * kL * 4; i += 64) {
    const double v = (double)modes_h[i];
    sEM[i / (kL * 4)][(i >> 2) % kL][i & 3] = make_double2(exp(v), exp(-v));
  }
  if (tid == 0) build_selB(selp, sB);
  __syncthreads();
  for (int i = tid; i < kL * 16; i += 64) {
    const int l = i >> 4, p = i & 15, nw = p >> 2, od = p & 3;
    sFH[l][p] = sEH[l][nw].x * sEH[l][od].y;
#pragma unroll
    for (int m = 0; m < kM; ++m)
      sFM[m][l][p] = make_double2(sEM[m][l][nw].x * sEM[m][l][od].y,
                                  sEM[m][l][nw].y * sEM[m][l][od].x);
  }
  __syncthreads();

  const int n = blockIdx.x * 64 + tid;
  double bb[kR][4];
#pragma unroll
  for (int r = 0; r < kR; ++r)
#pragma unroll
    for (int m = 0; m < 4; ++m) bb[r][m] = sB[r][m];

  unsigned w0 = 0, w1 = 0, w2 = 0;
  {
    const float4* ch = (const float4*)(chains + (size_t)n * (kL * 4));
#pragma unroll
    for (int l = 0; l < kL; ++l) {
      const float4 v = ch[l];
      const unsigned c = (v.y > 0.5f) ? 1u : ((v.z > 0.5f) ? 2u : ((v.w > 0.5f) ? 3u : 0u));
      const unsigned sh = 2u * (unsigned)(l & 15);
      if (l < 16) w0 |= c << sh; else if (l < 32) w1 |= c << sh; else w2 |= c << sh;
    }
  }
  double e0 = 1.0, e1 = 1.0, e2 = 1.0, e3 = 1.0;
  double d0 = 1.0, d1 = 1.0, d2 = 1.0, d3 = 1.0;
#pragma unroll 4
  for (int l = 0; l < kL; ++l) {
    const unsigned c = catAt(w0, w1, w2, (unsigned)l);
    const double2 t0 = sEM[0][l][c], t1 = sEM[1][l][c];
    const double2 t2 = sEM[2][l][c], t3 = sEM[3][l][c];
    e0 *= t0.x; d0 *= t0.y;  e1 *= t1.x; d1 *= t1.y;
    e2 *= t2.x; d2 *= t2.y;  e3 *= t3.x; d3 *= t3.y;
  }
  double Dd = pow7((d0 + d1) + (d2 + d3));
#pragma unroll
  for (int r = 0; r < kR; ++r)
    Dd *= (fma(bb[r][1], e1, bb[r][0] * e0) + fma(bb[r][3], e3, bb[r][2] * e2));

  for (int s = 0; s < kSteps; ++s) {
    const unsigned sh = P.shamt[s], wi = P.widx[s];
    const unsigned site = (P.rowbase[s] / 1280u);
    const unsigned dw = (rb32(P.keys[s][2], P.keys[s][3], (unsigned)n) & 0xFFFFFE00u) |
                        (rb32(P.keys[s][0], P.keys[s][1], (unsigned)n) & 3u);
    const unsigned nc = dw & 3u;
    const unsigned ww = (wi == 0u) ? w0 : ((wi == 1u) ? w1 : w2);
    const unsigned oldc = (ww >> sh) & 3u;
    const unsigned idx = nc * 4u + oldc;
    const double fh_c = sFH[site][idx];
    const double2 fm0 = sFM[0][site][idx], fm1 = sFM[1][site][idx];
    const double2 fm2 = sFM[2][site][idx], fm3 = sFM[3][site][idx];

    const float rndf = __uint_as_float((dw >> 9) | 0x3F800000u) - 1.0f;
    const double f0 = e0 * fm0.x, g0 = d0 * fm0.y;
    const double f1 = e1 * fm1.x, g1 = d1 * fm1.y;
    const double f2 = e2 * fm2.x, g2 = d2 * fm2.y;
    const double f3 = e3 * fm3.x, g3 = d3 * fm3.y;
    double se[kR];
#pragma unroll
    for (int r = 0; r < kR; ++r)
      se[r] = fma(bb[r][1], f1, bb[r][0] * f0) + fma(bb[r][3], f3, bb[r][2] * f2);
    const double PQ = (pow7((g0 + g1) + (g2 + g3)) *
                       ((se[0] * se[1]) * (se[2] * se[3]))) *
                      ((se[4] * se[5]) * se[6]);
    const double N = fh_c * PQ;
    const bool acc = N > (double)rndf * Dd;

    const unsigned mb = 3u << sh, nv = nc << sh;
    const unsigned wnew = (ww & ~mb) | nv;
    w0 = (acc && wi == 0u) ? wnew : w0;
    w1 = (acc && wi == 1u) ? wnew : w1;
    w2 = (acc && wi == 2u) ? wnew : w2;
    e0 = acc ? f0 : e0; e1 = acc ? f1 : e1; e2 = acc ? f2 : e2; e3 = acc ? f3 : e3;
    d0 = acc ? g0 : d0; d1 = acc ? g1 : d1; d2 = acc ? g2 : d2; d3 = acc ? g3 : d3;
    Dd = acc ? PQ : Dd;
  }

  float4* o = (float4*)(out + (size_t)n * (kL * 4));
#pragma unroll
  for (int l = 0; l < kL; ++l) {
    const unsigned c = catAt(w0, w1, w2, (unsigned)l);
    o[l] = make_float4(c == 0u ? 1.0f : 0.0f, c == 1u ? 1.0f : 0.0f,
                       c == 2u ? 1.0f : 0.0f, c == 3u ? 1.0f : 0.0f);
  }
}

extern "C" void kernel_launch(void* const* d_in, const int* in_sizes, int n_in,
                              void* d_out, int out_size, void* d_ws, size_t ws_size,
                              hipStream_t stream) {
  const float* chains  = (const float*)d_in[0];
  const float* h0      = (const float*)d_in[1];
  const float* modes_h = (const float*)d_in[2];
  const void*  sel     = d_in[3];
  (void)in_sizes; (void)n_in; (void)out_size;

  // ---- host-side wave-uniform PRNG metadata (bit-identical threefry) ----
  StepMeta P;
  for (unsigned s = 0; s < (unsigned)kSteps; ++s) {
    unsigned ka, kb, i0, i1, r0, r1, a0, a1, c0, c1;
    tf2(0u, 42u, 0u, s, ka, kb);                            // split(key(42),48)[s]
    tf2(ka, kb, 0u, 0u, i0, i1);                            // k_idx
    tf2(ka, kb, 0u, 1u, r0, r1);                            // k_res
    tf2(ka, kb, 0u, 2u, a0, a1);                            // k_acc
    unsigned h1a, h1b, l1a, l1b;
    tf2(i0, i1, 0u, 0u, h1a, h1b);
    tf2(i0, i1, 0u, 1u, l1a, l1b);
    const unsigned hb = rb32(h1a, h1b, 0u);
    const unsigned lb = rb32(l1a, l1b, 0u);
    const unsigned site = ((hb % 48u) * 16u + (lb % 48u)) % 48u;
    tf2(r0, r1, 0u, 1u, c0, c1);                            // k2 of split(k_res,2)
    P.rowbase[s] = site * 1280u;
    P.shamt[s]   = 2u * (site & 15u);
    P.widx[s]    = (site < 16u) ? 0u : ((site < 32u) ? 1u : 2u);
    P.keys[s][0] = c0; P.keys[s][1] = c1; P.keys[s][2] = a0; P.keys[s][3] = a1;
  }

  const size_t need = (size_t)kSteps * kN * sizeof(unsigned);  // 3 MB
  if (ws_size >= need) {
    unsigned* draws = (unsigned*)d_ws;
    draw_kernel<<<dim3(kN / 256, kSteps), dim3(256), 0, stream>>>(P, draws);
    mcmc_best<<<dim3(kN / 64), dim3(64), 0, stream>>>(
        chains, h0, modes_h, sel, draws, P, (float*)d_out);
  } else {
    mcmc_loop<<<dim3(kN / 64), dim3(64), 0, stream>>>(
        chains, h0, modes_h, sel, P, (float*)d_out);
  }
}